// Round 8
// baseline (37.050 us; speedup 1.0000x reference)
//
#include <hip/hip_runtime.h>
#include <hip/hip_bf16.h>

#define HWDIM 512
#define NWIN 50        // windows per dim: (512-20)/10 + 1
#define NT 51          // 10x10 tiles per dim covering rows/cols 0..509
#define NBC 48         // B*C = 16*3
#define NSTRIPE (NBC * NT)   // 2448 blocks, 1 stripe each
#define EPSV 1e-5f

typedef float f32x4 __attribute__((ext_vector_type(4)));

// ws layout: [0] int cnt; floats [64..111] acc[48]; [128..] tiles4[48*51*51] float4

// ---------------------------------------------------------------------------
// Pass 1: per-(plane, 10-row stripe) tile sums.
// Thread t: col4 = t&127 (cols 4c..4c+3), row-half rh = t>>7, rows 2*it+rh.
// The 15 float4 loads are issued via inline asm so the compiler CANNOT sink
// them to their uses (VGPR_Count is the execution check: must be >=80).
// Consumers are pinned below s_waitcnt vmcnt(0) + sched_barrier(0) (rule:
// compiler inserts no hazard waits for asm-defined values).
// Tile-split pattern: f=c4%5: f=0,1 all in tile 2k; f=2 splits lo/hi;
// f=3,4 in tile 2k+1. Tile records padded to float4 {cc, ce, ee, 0}.
// ---------------------------------------------------------------------------
__global__ __launch_bounds__(256) void tile_kernel(const float* __restrict__ C,
                                                   const float* __restrict__ E,
                                                   const float* __restrict__ M,
                                                   float4* __restrict__ tiles4,
                                                   int* __restrict__ cnt) {
    int t = threadIdx.x;
    if (blockIdx.x == 0 && t == 0) *cnt = 0;   // for pass-2 last-arriver

    int blk   = blockIdx.x;        // stripe id = plane*NT + ty
    int plane = blk / NT;
    int ty    = blk % NT;
    int c4    = t & 127;
    int rh    = t >> 7;
    bool isf2 = ((c4 % 5) == 2);

    size_t base = ((size_t)plane * HWDIM + (size_t)ty * 10 + rh) * HWDIM + 4 * c4;

    f32x4 cv[5], ev[5], mv[5];
    #pragma unroll
    for (int it = 0; it < 5; ++it) {
        const float* pc = C + base + (size_t)(2 * it) * HWDIM;
        const float* pe = E + base + (size_t)(2 * it) * HWDIM;
        const float* pm = M + base + (size_t)(2 * it) * HWDIM;
        asm volatile("global_load_dwordx4 %0, %1, off" : "=v"(cv[it]) : "v"(pc));
        asm volatile("global_load_dwordx4 %0, %1, off" : "=v"(ev[it]) : "v"(pe));
        asm volatile("global_load_dwordx4 %0, %1, off" : "=v"(mv[it]) : "v"(pm));
    }
    asm volatile("s_waitcnt vmcnt(0)" ::: "memory");
    __builtin_amdgcn_sched_barrier(0);

    float s01[3] = {0.f, 0.f, 0.f};
    float s23[3] = {0.f, 0.f, 0.f};
    #pragma unroll
    for (int it = 0; it < 5; ++it) {
        f32x4 c = cv[it], e = ev[it], m = mv[it];
        float mcx = m.x * c.x, mcy = m.y * c.y, mcz = m.z * c.z, mcw = m.w * c.w;
        float mex = m.x * e.x, mey = m.y * e.y, mez = m.z * e.z, mew = m.w * e.w;
        s01[0] = fmaf(mcx, c.x, s01[0]); s01[0] = fmaf(mcy, c.y, s01[0]);
        s01[1] = fmaf(mcx, e.x, s01[1]); s01[1] = fmaf(mcy, e.y, s01[1]);
        s01[2] = fmaf(mex, e.x, s01[2]); s01[2] = fmaf(mey, e.y, s01[2]);
        s23[0] = fmaf(mcz, c.z, s23[0]); s23[0] = fmaf(mcw, c.w, s23[0]);
        s23[1] = fmaf(mcz, e.z, s23[1]); s23[1] = fmaf(mcw, e.w, s23[1]);
        s23[2] = fmaf(mez, e.z, s23[2]); s23[2] = fmaf(mew, e.w, s23[2]);
    }

    __shared__ float lds[256 * 6];
    #pragma unroll
    for (int comp = 0; comp < 3; ++comp) {
        float lo = s01[comp] + (isf2 ? 0.f : s23[comp]);
        float hi = isf2 ? s23[comp] : 0.f;
        lds[t * 6 + comp]     = lo;
        lds[t * 6 + 3 + comp] = hi;
    }
    __syncthreads();

    if (t < NT) {                  // 51 threads: one float4 store per tile
        int tx = t;
        int k  = tx >> 1;
        float sums[3];
        #pragma unroll
        for (int comp = 0; comp < 3; ++comp) {
            float s;
            if ((tx & 1) == 0) {
                int b = 5 * k;
                s = lds[b * 6 + comp] + lds[(b + 1) * 6 + comp] + lds[(b + 2) * 6 + comp]
                  + lds[(b + 128) * 6 + comp] + lds[(b + 129) * 6 + comp] + lds[(b + 130) * 6 + comp];
            } else {
                int b = 5 * k + 2;
                s = lds[b * 6 + 3 + comp] + lds[(b + 1) * 6 + comp] + lds[(b + 2) * 6 + comp]
                  + lds[(b + 128) * 6 + 3 + comp] + lds[(b + 129) * 6 + comp] + lds[(b + 130) * 6 + comp];
            }
            sums[comp] = s;
        }
        tiles4[(size_t)blk * NT + tx] = make_float4(sums[0], sums[1], sums[2], 0.f);
    }
}

// ---------------------------------------------------------------------------
// Pass 2 (fused window + final): 48 blocks, one per plane. Stage the plane's
// 51x51 float4 tile grid in LDS via one coalesced burst, then compute all
// 2500 windows from LDS. Last-arriving block computes the deterministic
// fixed-order 48-way mean.
// ---------------------------------------------------------------------------
__global__ __launch_bounds__(256) void window_final_kernel(const float4* __restrict__ tiles4,
                                                           float* __restrict__ acc,
                                                           int* __restrict__ cnt,
                                                           float* __restrict__ out) {
    int plane = blockIdx.x;
    int t     = threadIdx.x;

    __shared__ float4 lt[NT * NT];               // 41616 B
    const float4* tp4 = tiles4 + (size_t)plane * NT * NT;
    #pragma unroll
    for (int k = 0; k < 11; ++k) {               // 11*256 >= 2601
        int i = t + k * 256;
        if (i < NT * NT) lt[i] = tp4[i];
    }
    __syncthreads();

    float ssq = 0.0f, tot = 0.0f;
    #pragma unroll
    for (int k = 0; k < 10; ++k) {               // 10*256 >= 2500
        int w = t + k * 256;
        if (w < NWIN * NWIN) {
            int wy = w / NWIN, wx = w % NWIN;
            float4 a = lt[wy * NT + wx];
            float4 b = lt[wy * NT + wx + 1];
            float4 c = lt[(wy + 1) * NT + wx];
            float4 d = lt[(wy + 1) * NT + wx + 1];
            float s_cc = a.x + b.x + c.x + d.x;
            float s_ce = a.y + b.y + c.y + d.y;
            float s_ee = a.z + b.z + c.z + d.z;
            float a2v = (s_ee > EPSV) ? (s_ce * s_ce / s_ee) : 0.0f;
            ssq += s_cc - a2v;
            tot += s_cc;
        }
    }

    #pragma unroll
    for (int d = 1; d < 64; d <<= 1) {
        ssq += __shfl_xor(ssq, d);
        tot += __shfl_xor(tot, d);
    }
    __shared__ float sr[8];
    __shared__ int   sflag;
    int lane = t & 63, wave = t >> 6;
    if (lane == 0) { sr[wave] = ssq; sr[4 + wave] = tot; }
    __syncthreads();

    if (t == 0) {
        float S = sr[0] + sr[1] + sr[2] + sr[3];
        float T = sr[4] + sr[5] + sr[6] + sr[7];
        acc[plane] = S / T;
        __threadfence();                     // release acc[plane]
        sflag = (atomicAdd(cnt, 1) == NBC - 1);
    }
    __syncthreads();
    if (!sflag) return;

    __threadfence();                         // acquire peers' acc
    if (t < 64) {
        float r = (t < NBC) ? *(volatile const float*)(acc + t) : 0.0f;
        #pragma unroll
        for (int d = 1; d < 64; d <<= 1) r += __shfl_xor(r, d);
        if (t == 0) out[0] = r / (float)NBC;
    }
}

extern "C" void kernel_launch(void* const* d_in, const int* in_sizes, int n_in,
                              void* d_out, int out_size, void* d_ws, size_t ws_size,
                              hipStream_t stream) {
    const float* correct  = (const float*)d_in[0];
    const float* estimate = (const float*)d_in[1];
    const float* mask     = (const float*)d_in[2];
    float* out = (float*)d_out;

    int*    cnt    = (int*)d_ws;                 // 1 int
    float*  acc    = (float*)d_ws + 64;          // 48 floats
    float4* tiles4 = (float4*)((float*)d_ws + 128); // 48*51*51 float4 ~ 2.0 MB

    tile_kernel<<<NSTRIPE, 256, 0, stream>>>(correct, estimate, mask, tiles4, cnt);
    window_final_kernel<<<NBC, 256, 0, stream>>>(tiles4, acc, cnt, out);
}